// Round 13
// baseline (1469.371 us; speedup 1.0000x reference)
//
#include <hip/hip_runtime.h>
#include <cmath>

constexpr int NN   = 100000;
constexpr int NE   = 3200000;
constexpr int DIN  = 128;
constexpr int DH   = 32;
constexpr int DOUT = 20;

constexpr int NB    = 392;                 // coarse buckets: dst>>8 -> 0..390 (+1 pad)
constexpr int NBUSE = (NN + 255) / 256;    // 391 buckets actually used
constexpr int NBLK  = 256;                 // phase A/C blocks
constexpr int SLICE = NE / NBLK;           // 12500 edges per block (exact)

constexpr int NPB = 64;                    // nodes per lin1 block
constexpr int XSB = 136;                   // bf16 LDS row stride (16B-aligned, 2-way banks)
constexpr int PPB = 64;                    // nodes per post block (4 lanes/node)

typedef __attribute__((ext_vector_type(8))) short short8v;   // 8 bf16 (4 VGPRs)
typedef __attribute__((ext_vector_type(4))) float f32x4;     // MFMA accumulator

__device__ inline unsigned short f2bf(float f) {           // RNE float->bf16
    unsigned u = __builtin_bit_cast(unsigned, f);
    unsigned r = 0x7FFFu + ((u >> 16) & 1u);
    return (unsigned short)((u + r) >> 16);
}
__device__ inline float bflo(unsigned u) {                 // low ushort -> float
    return __builtin_bit_cast(float, u << 16);
}
__device__ inline float bfhi(unsigned u) {                 // high ushort -> float
    return __builtin_bit_cast(float, u & 0xFFFF0000u);
}

// ---------------- layer-1 projections via MFMA: xl(bf16)=x@W1l, xr(f32)=x@W1r ----------
__global__ __launch_bounds__(256, 4) void lin1_kernel(
    const float* __restrict__ x, const float* __restrict__ Wl,
    const float* __restrict__ Wr, unsigned short* __restrict__ xlbf,
    float* __restrict__ xr)
{
    __shared__ unsigned short xs[NPB * XSB];   // 17408 B
    int t = threadIdx.x;
    int nodeBase = blockIdx.x * NPB;

    const float4* x4 = reinterpret_cast<const float4*>(x) + (size_t)nodeBase * (DIN / 4);
    for (int i = t; i < NPB * (DIN / 4); i += 256) {
        int n = i >> 5, c = i & 31;
        float4 v = make_float4(0.f, 0.f, 0.f, 0.f);
        if (nodeBase + n < NN) v = x4[i];
        unsigned lo = (unsigned)f2bf(v.x) | ((unsigned)f2bf(v.y) << 16);
        unsigned hi = (unsigned)f2bf(v.z) | ((unsigned)f2bf(v.w) << 16);
        *reinterpret_cast<uint2*>(&xs[n * XSB + c * 4]) = make_uint2(lo, hi);
    }
    __syncthreads();

    int wv   = t >> 6;                 // 0..3
    int lane = t & 63;
    const float* W = (wv & 2) ? Wr : Wl;
    int jbase = (wv & 1) * 16;
    int ncol  = jbase + (lane & 15);   // B: col = lane&15
    int krow  = (lane >> 4) * 8;       // B/A: k-chunk = (lane>>4)*8

    short8v bfrag[4];
#pragma unroll
    for (int ks = 0; ks < 4; ++ks) {
        const float* wp = W + (ks * 32 + krow) * DH + ncol;
        short8v f;
#pragma unroll
        for (int e = 0; e < 8; ++e) f[e] = (short)f2bf(wp[e * DH]);
        bfrag[ks] = f;
    }

    f32x4 acc[4];
#pragma unroll
    for (int m = 0; m < 4; ++m) acc[m] = f32x4{0.f, 0.f, 0.f, 0.f};

#pragma unroll
    for (int m = 0; m < 4; ++m) {
        int row = m * 16 + (lane & 15);
#pragma unroll
        for (int ks = 0; ks < 4; ++ks) {
            short8v a = *reinterpret_cast<const short8v*>(&xs[row * XSB + ks * 32 + krow]);
            acc[m] = __builtin_amdgcn_mfma_f32_16x16x32_bf16(a, bfrag[ks], acc[m], 0, 0, 0);
        }
    }

#pragma unroll
    for (int m = 0; m < 4; ++m) {
        int rbase = m * 16 + (lane >> 4) * 4;
#pragma unroll
        for (int r = 0; r < 4; ++r) {
            int node = nodeBase + rbase + r;
            if (node < NN) {
                float v = acc[m][r];
                if (wv & 2) xr[(size_t)node * DH + ncol] = v;
                else        xlbf[(size_t)node * DH + ncol] = f2bf(v);
            }
        }
    }
}

// ---------------- phase A: per-block coarse-bucket histogram ----------------
__global__ __launch_bounds__(256) void countA_kernel(
    const int* __restrict__ ei, int* __restrict__ counts)
{
    __shared__ int h[NB];
    int blk = blockIdx.x, t = threadIdx.x;
    for (int i = t; i < NB; i += 256) h[i] = 0;
    __syncthreads();
    int base = blk * SLICE;
    for (int i = base + t; i < base + SLICE; i += 256) {
        int dst = ei[NE + i];
        atomicAdd(&h[dst >> 8], 1);
    }
    __syncthreads();
    for (int i = t; i < NB; i += 256) counts[blk * NB + i] = h[i];
}

// ------- phase B1: per-bucket exclusive scan over 256 block counts -------
__global__ __launch_bounds__(256) void scanB1_kernel(
    const int* __restrict__ counts, int* __restrict__ offs, int* __restrict__ totals)
{
    __shared__ int sdata[256];
    int b = blockIdx.x, t = threadIdx.x;
    int v = counts[t * NB + b];
    sdata[t] = v;
    __syncthreads();
    for (int off = 1; off < 256; off <<= 1) {
        int tmp = (t >= off) ? sdata[t - off] : 0;
        __syncthreads();
        sdata[t] += tmp;
        __syncthreads();
    }
    offs[b * 256 + t] = sdata[t] - v;
    if (t == 255) totals[b] = sdata[255];
}

// ------- phase B2: exclusive scan of bucket totals (tiny) -------
__global__ void scanB2_kernel(const int* __restrict__ totals, int* __restrict__ bases)
{
    if (threadIdx.x == 0 && blockIdx.x == 0) {
        int acc = 0;
        for (int i = 0; i < NB; ++i) { bases[i] = acc; acc += totals[i]; }
        bases[NB] = acc;
    }
}

// ------- phase C: rank-based scatter into per-(block,bucket) private regions -------
__global__ __launch_bounds__(256) void scatterC_kernel(
    const int* __restrict__ ei, const int* __restrict__ offs,
    const int* __restrict__ bases, unsigned* __restrict__ csrtmp)
{
    __shared__ int cnt[NB];
    __shared__ int wbase[NB];
    int blk = blockIdx.x, t = threadIdx.x;
    for (int i = t; i < NB; i += 256) {
        cnt[i] = 0;
        wbase[i] = bases[i] + offs[i * 256 + blk];
    }
    __syncthreads();
    int base = blk * SLICE;
    for (int i = base + t; i < base + SLICE; i += 256) {
        int dst = ei[NE + i];
        int src = ei[i];
        int b = dst >> 8;
        int r = atomicAdd(&cnt[b], 1);                       // LDS atomic
        csrtmp[wbase[b] + r] = ((unsigned)(dst & 255) << 17) | (unsigned)src;
    }
}

// ------- edge-parallel gather: one block per 256-node bucket, LDS f32 accum -------
// feat rows are bf16 (64 B). 8 threads/edge; swizzled LDS chunk position
// ((c + dl) & 7) spreads the 8 random-dst lanes across banks.
template<bool DO_DEG>
__global__ __launch_bounds__(1024) void gatherLDS_kernel(
    const unsigned* __restrict__ csrtmp, const int* __restrict__ bases,
    const uint2* __restrict__ feat, float* __restrict__ agg, int* __restrict__ deg)
{
    __shared__ float acc[256 * DH];        // 32 KB
    __shared__ int   ldeg[256];
    int b = blockIdx.x, t = threadIdx.x;
    for (int i = t; i < 256 * DH; i += 1024) acc[i] = 0.f;
    if (DO_DEG && t < 256) ldeg[t] = 0;
    __syncthreads();

    int lo = bases[b], hi = bases[b + 1];
    int c = t & 7;
    for (int i = lo + (t >> 3); i < hi; i += 128) {
        unsigned u = csrtmp[i];
        int src = (int)(u & 0x1FFFFu);
        int dl  = (int)(u >> 17);
        uint2 v = feat[(size_t)src * 8 + c];
        int cs = ((c + dl) & 7) * 4;       // swizzled chunk position
        float* a = &acc[dl * DH + cs];
        atomicAdd(a + 0, bflo(v.x));
        atomicAdd(a + 1, bfhi(v.x));
        atomicAdd(a + 2, bflo(v.y));
        atomicAdd(a + 3, bfhi(v.y));
        if (DO_DEG && c == 0) atomicAdd(&ldeg[dl], 1);
    }
    __syncthreads();

    int nodeBase = b * 256;
    for (int i = t; i < 256 * DH; i += 1024) {
        int dl = i >> 5;
        int node = nodeBase + dl;
        if (node < NN) {
            int p = (i & 31) >> 2;                 // stored chunk position
            int j = i & 3;
            int clog = (p - dl) & 7;               // logical chunk
            agg[(size_t)node * DH + clog * 4 + j] = acc[i];
        }
    }
    if (DO_DEG && t < 256 && nodeBase + t < NN) deg[nodeBase + t] = ldeg[t];
}

// ---- post layer1 (4 lanes/node): o = agg/deg + b1 + xr; h1 = tanh(l2norm(o));
//      hl(bf16) = h1@W2l, hr(f32) = h1@W2r ----
__global__ __launch_bounds__(256) void post1_kernel(
    const float* __restrict__ agg, const int* __restrict__ deg,
    const float* __restrict__ xr, const float* __restrict__ b1,
    const float* __restrict__ W2l, const float* __restrict__ W2r,
    unsigned short* __restrict__ hlbf, float* __restrict__ hr)
{
    __shared__ float hs[PPB][DH + 1];
    int t = threadIdx.x;
    int n = t >> 2;                    // local node 0..63
    int sub = t & 3;                   // dim group: [sub*8, sub*8+8)
    int g = blockIdx.x * PPB + n;
    bool valid = g < NN;

    float o[8];
#pragma unroll
    for (int j = 0; j < 8; ++j) o[j] = 0.f;
    if (valid) {
        float inv = 1.0f / fmaxf((float)deg[g], 1.0f);
        const float4* ag4 = reinterpret_cast<const float4*>(agg + (size_t)g * DH + sub * 8);
        const float4* xr4 = reinterpret_cast<const float4*>(xr  + (size_t)g * DH + sub * 8);
        const float*  bp  = b1 + sub * 8;
#pragma unroll
        for (int q = 0; q < 2; ++q) {
            float4 a = ag4[q]; float4 r = xr4[q];
            o[q*4+0] = fmaf(a.x, inv, bp[q*4+0] + r.x);
            o[q*4+1] = fmaf(a.y, inv, bp[q*4+1] + r.y);
            o[q*4+2] = fmaf(a.z, inv, bp[q*4+2] + r.z);
            o[q*4+3] = fmaf(a.w, inv, bp[q*4+3] + r.w);
        }
    }
    float ss = 0.f;
#pragma unroll
    for (int j = 0; j < 8; ++j) ss += o[j] * o[j];
    ss += __shfl_xor(ss, 1);
    ss += __shfl_xor(ss, 2);
    float rn = 1.0f / fmaxf(sqrtf(ss), 1e-12f);
    float h[8];
#pragma unroll
    for (int j = 0; j < 8; ++j) h[j] = tanhf(o[j] * rn);
#pragma unroll
    for (int j = 0; j < 8; ++j) hs[n][sub * 8 + j] = h[j];
    __syncthreads();

    float al[8], ar[8];
#pragma unroll
    for (int j = 0; j < 8; ++j) { al[j] = 0.f; ar[j] = 0.f; }
    for (int k = 0; k < DH; ++k) {
        float hk = hs[n][k];
        const float4* wl4 = reinterpret_cast<const float4*>(W2l + k * DH + sub * 8);
        const float4* wr4 = reinterpret_cast<const float4*>(W2r + k * DH + sub * 8);
#pragma unroll
        for (int q = 0; q < 2; ++q) {
            float4 wl = wl4[q], wr = wr4[q];
            al[q*4+0] = fmaf(hk, wl.x, al[q*4+0]);
            al[q*4+1] = fmaf(hk, wl.y, al[q*4+1]);
            al[q*4+2] = fmaf(hk, wl.z, al[q*4+2]);
            al[q*4+3] = fmaf(hk, wl.w, al[q*4+3]);
            ar[q*4+0] = fmaf(hk, wr.x, ar[q*4+0]);
            ar[q*4+1] = fmaf(hk, wr.y, ar[q*4+1]);
            ar[q*4+2] = fmaf(hk, wr.z, ar[q*4+2]);
            ar[q*4+3] = fmaf(hk, wr.w, ar[q*4+3]);
        }
    }
    if (valid) {
        unsigned pk[4];
#pragma unroll
        for (int q = 0; q < 4; ++q)
            pk[q] = (unsigned)f2bf(al[q*2]) | ((unsigned)f2bf(al[q*2+1]) << 16);
        *reinterpret_cast<uint4*>(hlbf + (size_t)g * DH + sub * 8) =
            make_uint4(pk[0], pk[1], pk[2], pk[3]);
        float4* hr4 = reinterpret_cast<float4*>(hr + (size_t)g * DH + sub * 8);
        hr4[0] = make_float4(ar[0], ar[1], ar[2], ar[3]);
        hr4[1] = make_float4(ar[4], ar[5], ar[6], ar[7]);
    }
}

// ---- post layer2 + classifier (4 lanes/node) ----
__global__ __launch_bounds__(256) void post2_kernel(
    const float* __restrict__ agg, const int* __restrict__ deg,
    const float* __restrict__ hr, const float* __restrict__ b2,
    const float* __restrict__ Wc, const float* __restrict__ bc,
    float* __restrict__ h2out, float* __restrict__ outp)
{
    __shared__ float hs[PPB][DH + 1];
    int t = threadIdx.x;
    int n = t >> 2;
    int sub = t & 3;
    int g = blockIdx.x * PPB + n;
    bool valid = g < NN;

    float o[8];
#pragma unroll
    for (int j = 0; j < 8; ++j) o[j] = 0.f;
    if (valid) {
        float inv = 1.0f / fmaxf((float)deg[g], 1.0f);
        const float4* ag4 = reinterpret_cast<const float4*>(agg + (size_t)g * DH + sub * 8);
        const float4* hr4 = reinterpret_cast<const float4*>(hr  + (size_t)g * DH + sub * 8);
        const float*  bp  = b2 + sub * 8;
#pragma unroll
        for (int q = 0; q < 2; ++q) {
            float4 a = ag4[q]; float4 r = hr4[q];
            o[q*4+0] = fmaf(a.x, inv, bp[q*4+0] + r.x);
            o[q*4+1] = fmaf(a.y, inv, bp[q*4+1] + r.y);
            o[q*4+2] = fmaf(a.z, inv, bp[q*4+2] + r.z);
            o[q*4+3] = fmaf(a.w, inv, bp[q*4+3] + r.w);
        }
    }
    float ss = 0.f;
#pragma unroll
    for (int j = 0; j < 8; ++j) ss += o[j] * o[j];
    ss += __shfl_xor(ss, 1);
    ss += __shfl_xor(ss, 2);
    float rn = 1.0f / fmaxf(sqrtf(ss), 1e-12f);
    float h[8];
#pragma unroll
    for (int j = 0; j < 8; ++j) h[j] = tanhf(o[j] * rn);
#pragma unroll
    for (int j = 0; j < 8; ++j) hs[n][sub * 8 + j] = h[j];
    if (valid) {
        float4* h2o = reinterpret_cast<float4*>(h2out + (size_t)g * DH + sub * 8);
        h2o[0] = make_float4(h[0], h[1], h[2], h[3]);
        h2o[1] = make_float4(h[4], h[5], h[6], h[7]);
    }
    __syncthreads();

    float z[5];
#pragma unroll
    for (int q = 0; q < 5; ++q) z[q] = bc[sub * 5 + q];
    for (int k = 0; k < DH; ++k) {
        float hk = hs[n][k];
        const float* wc = Wc + k * DOUT + sub * 5;
#pragma unroll
        for (int q = 0; q < 5; ++q) z[q] = fmaf(hk, wc[q], z[q]);
    }
    float m = z[0];
#pragma unroll
    for (int q = 1; q < 5; ++q) m = fmaxf(m, z[q]);
    m = fmaxf(m, __shfl_xor(m, 1));
    m = fmaxf(m, __shfl_xor(m, 2));
    float s = 0.f;
#pragma unroll
    for (int q = 0; q < 5; ++q) s += expf(z[q] - m);
    s += __shfl_xor(s, 1);
    s += __shfl_xor(s, 2);
    float lse = m + logf(s);
    if (valid) {
        float* orow = outp + (size_t)g * DOUT + sub * 5;
#pragma unroll
        for (int q = 0; q < 5; ++q) orow[q] = z[q] - lse;
    }
}

extern "C" void kernel_launch(void* const* d_in, const int* in_sizes, int n_in,
                              void* d_out, int out_size, void* d_ws, size_t ws_size,
                              hipStream_t stream) {
    const float* x   = (const float*)d_in[0];
    const int*   ei  = (const int*)d_in[1];
    const float* W1l = (const float*)d_in[2];
    const float* b1  = (const float*)d_in[3];
    const float* W1r = (const float*)d_in[4];
    const float* W2l = (const float*)d_in[5];
    const float* b2  = (const float*)d_in[6];
    const float* W2r = (const float*)d_in[7];
    const float* Wc  = (const float*)d_in[8];
    const float* bc  = (const float*)d_in[9];

    float* outp = (float*)d_out;                          // [NN, 20]
    float* hout = outp + (size_t)NN * DOUT;               // [NN, 32]

    // workspace layout (csrtmp now lives on its own — read during gathers)
    unsigned short* xlbf = (unsigned short*)d_ws;         // NN*DH bf16 (6.4 MB)
    float* xr      = (float*)(xlbf + (size_t)NN * DH);    // NN*DH f32 (also hr)
    float* agg     = xr + (size_t)NN * DH;                // NN*DH f32
    unsigned* csrtmp = (unsigned*)(agg + (size_t)NN * DH);// NE u32 (12.8 MB)
    int* deg       = (int*)(csrtmp + NE);                 // NN
    int* counts    = deg + NN;                            // NBLK*NB
    int* offs      = counts + NBLK * NB;                  // NB*NBLK
    int* totals    = offs + NB * NBLK;                    // NB
    int* bases     = totals + NB;                         // NB+1

    const int lin1Blocks = (NN + NPB - 1) / NPB;          // 1563
    const int postBlocks = (NN + PPB - 1) / PPB;          // 1563

    lin1_kernel<<<lin1Blocks, 256, 0, stream>>>(x, W1l, W1r, xlbf, xr);

    countA_kernel<<<NBLK, 256, 0, stream>>>(ei, counts);
    scanB1_kernel<<<NB, 256, 0, stream>>>(counts, offs, totals);
    scanB2_kernel<<<1, 64, 0, stream>>>(totals, bases);
    scatterC_kernel<<<NBLK, 256, 0, stream>>>(ei, offs, bases, csrtmp);

    gatherLDS_kernel<true><<<NBUSE, 1024, 0, stream>>>(csrtmp, bases,
                                                       (const uint2*)xlbf, agg, deg);
    post1_kernel<<<postBlocks, 256, 0, stream>>>(agg, deg, xr, b1, W2l, W2r, xlbf, xr);

    gatherLDS_kernel<false><<<NBUSE, 1024, 0, stream>>>(csrtmp, bases,
                                                        (const uint2*)xlbf, agg, deg);
    post2_kernel<<<postBlocks, 256, 0, stream>>>(agg, deg, xr, b2, Wc, bc, hout, outp);
}

// Round 14
// 227.966 us; speedup vs baseline: 6.4456x; 6.4456x over previous
//
#include <hip/hip_runtime.h>
#include <cmath>

constexpr int NN   = 100000;
constexpr int NE   = 3200000;
constexpr int DIN  = 128;
constexpr int DH   = 32;
constexpr int DOUT = 20;

constexpr int NB    = 392;                 // coarse buckets: dst>>8 -> 0..390 (+1 pad)
constexpr int NBUSE = (NN + 255) / 256;    // 391 buckets actually used
constexpr int NBLK  = 256;                 // phase A/C blocks
constexpr int SLICE = NE / NBLK;           // 12500 edges per block (exact)

constexpr int NPB = 64;                    // nodes per lin1 block
constexpr int XSB = 136;                   // bf16 LDS row stride (16B-aligned, 2-way banks)
constexpr int PPB = 64;                    // nodes per post block (4 lanes/node)

typedef __attribute__((ext_vector_type(8))) short short8v;   // 8 bf16 (4 VGPRs)
typedef __attribute__((ext_vector_type(4))) float f32x4;     // MFMA accumulator

__device__ inline unsigned short f2bf(float f) {           // RNE float->bf16
    unsigned u = __builtin_bit_cast(unsigned, f);
    unsigned r = 0x7FFFu + ((u >> 16) & 1u);
    return (unsigned short)((u + r) >> 16);
}
__device__ inline float bflo(unsigned u) {                 // low ushort -> float
    return __builtin_bit_cast(float, u << 16);
}
__device__ inline float bfhi(unsigned u) {                 // high ushort -> float
    return __builtin_bit_cast(float, u & 0xFFFF0000u);
}

// ---------------- layer-1 projections via MFMA: xl(bf16)=x@W1l, xr(f32)=x@W1r ----------
__global__ __launch_bounds__(256, 4) void lin1_kernel(
    const float* __restrict__ x, const float* __restrict__ Wl,
    const float* __restrict__ Wr, unsigned short* __restrict__ xlbf,
    float* __restrict__ xr)
{
    __shared__ unsigned short xs[NPB * XSB];   // 17408 B
    int t = threadIdx.x;
    int nodeBase = blockIdx.x * NPB;

    const float4* x4 = reinterpret_cast<const float4*>(x) + (size_t)nodeBase * (DIN / 4);
    for (int i = t; i < NPB * (DIN / 4); i += 256) {
        int n = i >> 5, c = i & 31;
        float4 v = make_float4(0.f, 0.f, 0.f, 0.f);
        if (nodeBase + n < NN) v = x4[i];
        unsigned lo = (unsigned)f2bf(v.x) | ((unsigned)f2bf(v.y) << 16);
        unsigned hi = (unsigned)f2bf(v.z) | ((unsigned)f2bf(v.w) << 16);
        *reinterpret_cast<uint2*>(&xs[n * XSB + c * 4]) = make_uint2(lo, hi);
    }
    __syncthreads();

    int wv   = t >> 6;                 // 0..3
    int lane = t & 63;
    const float* W = (wv & 2) ? Wr : Wl;
    int jbase = (wv & 1) * 16;
    int ncol  = jbase + (lane & 15);   // B: col = lane&15
    int krow  = (lane >> 4) * 8;       // B/A: k-chunk = (lane>>4)*8

    short8v bfrag[4];
#pragma unroll
    for (int ks = 0; ks < 4; ++ks) {
        const float* wp = W + (ks * 32 + krow) * DH + ncol;
        short8v f;
#pragma unroll
        for (int e = 0; e < 8; ++e) f[e] = (short)f2bf(wp[e * DH]);
        bfrag[ks] = f;
    }

    f32x4 acc[4];
#pragma unroll
    for (int m = 0; m < 4; ++m) acc[m] = f32x4{0.f, 0.f, 0.f, 0.f};

#pragma unroll
    for (int m = 0; m < 4; ++m) {
        int row = m * 16 + (lane & 15);
#pragma unroll
        for (int ks = 0; ks < 4; ++ks) {
            short8v a = *reinterpret_cast<const short8v*>(&xs[row * XSB + ks * 32 + krow]);
            acc[m] = __builtin_amdgcn_mfma_f32_16x16x32_bf16(a, bfrag[ks], acc[m], 0, 0, 0);
        }
    }

#pragma unroll
    for (int m = 0; m < 4; ++m) {
        int rbase = m * 16 + (lane >> 4) * 4;
#pragma unroll
        for (int r = 0; r < 4; ++r) {
            int node = nodeBase + rbase + r;
            if (node < NN) {
                float v = acc[m][r];
                if (wv & 2) xr[(size_t)node * DH + ncol] = v;
                else        xlbf[(size_t)node * DH + ncol] = f2bf(v);
            }
        }
    }
}

// ---------------- phase A: per-block coarse-bucket histogram ----------------
__global__ __launch_bounds__(256) void countA_kernel(
    const int* __restrict__ ei, int* __restrict__ counts)
{
    __shared__ int h[NB];
    int blk = blockIdx.x, t = threadIdx.x;
    for (int i = t; i < NB; i += 256) h[i] = 0;
    __syncthreads();
    int base = blk * SLICE;
    for (int i = base + t; i < base + SLICE; i += 256) {
        int dst = ei[NE + i];
        atomicAdd(&h[dst >> 8], 1);
    }
    __syncthreads();
    for (int i = t; i < NB; i += 256) counts[blk * NB + i] = h[i];
}

// ------- phase B1: per-bucket exclusive scan over 256 block counts -------
__global__ __launch_bounds__(256) void scanB1_kernel(
    const int* __restrict__ counts, int* __restrict__ offs, int* __restrict__ totals)
{
    __shared__ int sdata[256];
    int b = blockIdx.x, t = threadIdx.x;
    int v = counts[t * NB + b];
    sdata[t] = v;
    __syncthreads();
    for (int off = 1; off < 256; off <<= 1) {
        int tmp = (t >= off) ? sdata[t - off] : 0;
        __syncthreads();
        sdata[t] += tmp;
        __syncthreads();
    }
    offs[b * 256 + t] = sdata[t] - v;
    if (t == 255) totals[b] = sdata[255];
}

// ------- phase B2: exclusive scan of bucket totals (tiny) -------
__global__ void scanB2_kernel(const int* __restrict__ totals, int* __restrict__ bases)
{
    if (threadIdx.x == 0 && blockIdx.x == 0) {
        int acc = 0;
        for (int i = 0; i < NB; ++i) { bases[i] = acc; acc += totals[i]; }
        bases[NB] = acc;
    }
}

// ------- phase C: rank-based scatter into per-(block,bucket) private regions -------
__global__ __launch_bounds__(256) void scatterC_kernel(
    const int* __restrict__ ei, const int* __restrict__ offs,
    const int* __restrict__ bases, unsigned* __restrict__ csrtmp)
{
    __shared__ int cnt[NB];
    __shared__ int wbase[NB];
    int blk = blockIdx.x, t = threadIdx.x;
    for (int i = t; i < NB; i += 256) {
        cnt[i] = 0;
        wbase[i] = bases[i] + offs[i * 256 + blk];
    }
    __syncthreads();
    int base = blk * SLICE;
    for (int i = base + t; i < base + SLICE; i += 256) {
        int dst = ei[NE + i];
        int src = ei[i];
        int b = dst >> 8;
        int r = atomicAdd(&cnt[b], 1);                       // LDS atomic
        csrtmp[wbase[b] + r] = ((unsigned)(dst & 255) << 17) | (unsigned)src;
    }
}

// ------- phase D: regroup within bucket -> final CSR + start + deg -------
__global__ __launch_bounds__(256) void regroupD_kernel(
    const unsigned* __restrict__ csrtmp, const int* __restrict__ bases,
    int* __restrict__ csrsrc, int* __restrict__ deg, int* __restrict__ start)
{
    __shared__ int h[256];
    __shared__ int sdata[256];
    int b = blockIdx.x, t = threadIdx.x;
    int lo = bases[b], hi = bases[b + 1];
    h[t] = 0;
    __syncthreads();
    for (int i = lo + t; i < hi; i += 256)
        atomicAdd(&h[csrtmp[i] >> 17], 1);
    __syncthreads();
    int v = h[t];
    sdata[t] = v;
    __syncthreads();
    for (int off = 1; off < 256; off <<= 1) {
        int tmp = (t >= off) ? sdata[t - off] : 0;
        __syncthreads();
        sdata[t] += tmp;
        __syncthreads();
    }
    int ex = sdata[t] - v;
    int node = b * 256 + t;
    if (node < NN) { start[node] = lo + ex; deg[node] = v; }
    h[t] = ex;
    __syncthreads();
    for (int i = lo + t; i < hi; i += 256) {
        unsigned u = csrtmp[i];
        int r = atomicAdd(&h[u >> 17], 1);   // LDS atomic
        csrsrc[lo + r] = (int)(u & 0x1FFFFu);
    }
}

// ------- gather (bf16 feat rows, 64 B/row), 4-way unrolled for MLP -------
__global__ __launch_bounds__(256) void gather_kernel(
    const int* __restrict__ start, const int* __restrict__ deg,
    const int* __restrict__ csrsrc, const unsigned short* __restrict__ feat,
    float* __restrict__ agg)
{
    int tid = blockIdx.x * 256 + threadIdx.x;
    int g = tid >> 3;            // node
    int c = tid & 7;             // uint2 chunk (4 bf16) of the 32-dim row
    if (g >= NN) return;
    int s = start[g];
    int e = s + deg[g];
    const uint2* f2 = reinterpret_cast<const uint2*>(feat);
    float4 a0 = make_float4(0.f, 0.f, 0.f, 0.f);
    float4 a1 = make_float4(0.f, 0.f, 0.f, 0.f);
    float4 a2 = make_float4(0.f, 0.f, 0.f, 0.f);
    float4 a3 = make_float4(0.f, 0.f, 0.f, 0.f);
    int i = s;
    for (; i + 4 <= e; i += 4) {
        int s0 = csrsrc[i];
        int s1 = csrsrc[i + 1];
        int s2 = csrsrc[i + 2];
        int s3 = csrsrc[i + 3];
        uint2 v0 = f2[(size_t)s0 * 8 + c];
        uint2 v1 = f2[(size_t)s1 * 8 + c];
        uint2 v2 = f2[(size_t)s2 * 8 + c];
        uint2 v3 = f2[(size_t)s3 * 8 + c];
        a0.x += bflo(v0.x); a0.y += bfhi(v0.x); a0.z += bflo(v0.y); a0.w += bfhi(v0.y);
        a1.x += bflo(v1.x); a1.y += bfhi(v1.x); a1.z += bflo(v1.y); a1.w += bfhi(v1.y);
        a2.x += bflo(v2.x); a2.y += bfhi(v2.x); a2.z += bflo(v2.y); a2.w += bfhi(v2.y);
        a3.x += bflo(v3.x); a3.y += bfhi(v3.x); a3.z += bflo(v3.y); a3.w += bfhi(v3.y);
    }
    for (; i < e; ++i) {
        int s0 = csrsrc[i];
        uint2 v0 = f2[(size_t)s0 * 8 + c];
        a0.x += bflo(v0.x); a0.y += bfhi(v0.x); a0.z += bflo(v0.y); a0.w += bfhi(v0.y);
    }
    a0.x += a1.x + a2.x + a3.x;
    a0.y += a1.y + a2.y + a3.y;
    a0.z += a1.z + a2.z + a3.z;
    a0.w += a1.w + a2.w + a3.w;
    reinterpret_cast<float4*>(agg)[(size_t)g * 8 + c] = a0;
}

// ---- post layer1 (4 lanes/node): o = agg/deg + b1 + xr; h1 = tanh(l2norm(o));
//      hl(bf16) = h1@W2l, hr(f32) = h1@W2r ----
__global__ __launch_bounds__(256) void post1_kernel(
    const float* __restrict__ agg, const int* __restrict__ deg,
    const float* __restrict__ xr, const float* __restrict__ b1,
    const float* __restrict__ W2l, const float* __restrict__ W2r,
    unsigned short* __restrict__ hlbf, float* __restrict__ hr)
{
    __shared__ float hs[PPB][DH + 1];
    int t = threadIdx.x;
    int n = t >> 2;                    // local node 0..63
    int sub = t & 3;                   // dim group: [sub*8, sub*8+8)
    int g = blockIdx.x * PPB + n;
    bool valid = g < NN;

    float o[8];
#pragma unroll
    for (int j = 0; j < 8; ++j) o[j] = 0.f;
    if (valid) {
        float inv = 1.0f / fmaxf((float)deg[g], 1.0f);
        const float4* ag4 = reinterpret_cast<const float4*>(agg + (size_t)g * DH + sub * 8);
        const float4* xr4 = reinterpret_cast<const float4*>(xr  + (size_t)g * DH + sub * 8);
        const float*  bp  = b1 + sub * 8;
#pragma unroll
        for (int q = 0; q < 2; ++q) {
            float4 a = ag4[q]; float4 r = xr4[q];
            o[q*4+0] = fmaf(a.x, inv, bp[q*4+0] + r.x);
            o[q*4+1] = fmaf(a.y, inv, bp[q*4+1] + r.y);
            o[q*4+2] = fmaf(a.z, inv, bp[q*4+2] + r.z);
            o[q*4+3] = fmaf(a.w, inv, bp[q*4+3] + r.w);
        }
    }
    float ss = 0.f;
#pragma unroll
    for (int j = 0; j < 8; ++j) ss += o[j] * o[j];
    ss += __shfl_xor(ss, 1);
    ss += __shfl_xor(ss, 2);
    float rn = 1.0f / fmaxf(sqrtf(ss), 1e-12f);
    float h[8];
#pragma unroll
    for (int j = 0; j < 8; ++j) h[j] = tanhf(o[j] * rn);
#pragma unroll
    for (int j = 0; j < 8; ++j) hs[n][sub * 8 + j] = h[j];
    __syncthreads();

    float al[8], ar[8];
#pragma unroll
    for (int j = 0; j < 8; ++j) { al[j] = 0.f; ar[j] = 0.f; }
    for (int k = 0; k < DH; ++k) {
        float hk = hs[n][k];
        const float4* wl4 = reinterpret_cast<const float4*>(W2l + k * DH + sub * 8);
        const float4* wr4 = reinterpret_cast<const float4*>(W2r + k * DH + sub * 8);
#pragma unroll
        for (int q = 0; q < 2; ++q) {
            float4 wl = wl4[q], wr = wr4[q];
            al[q*4+0] = fmaf(hk, wl.x, al[q*4+0]);
            al[q*4+1] = fmaf(hk, wl.y, al[q*4+1]);
            al[q*4+2] = fmaf(hk, wl.z, al[q*4+2]);
            al[q*4+3] = fmaf(hk, wl.w, al[q*4+3]);
            ar[q*4+0] = fmaf(hk, wr.x, ar[q*4+0]);
            ar[q*4+1] = fmaf(hk, wr.y, ar[q*4+1]);
            ar[q*4+2] = fmaf(hk, wr.z, ar[q*4+2]);
            ar[q*4+3] = fmaf(hk, wr.w, ar[q*4+3]);
        }
    }
    if (valid) {
        unsigned pk[4];
#pragma unroll
        for (int q = 0; q < 4; ++q)
            pk[q] = (unsigned)f2bf(al[q*2]) | ((unsigned)f2bf(al[q*2+1]) << 16);
        *reinterpret_cast<uint4*>(hlbf + (size_t)g * DH + sub * 8) =
            make_uint4(pk[0], pk[1], pk[2], pk[3]);
        float4* hr4 = reinterpret_cast<float4*>(hr + (size_t)g * DH + sub * 8);
        hr4[0] = make_float4(ar[0], ar[1], ar[2], ar[3]);
        hr4[1] = make_float4(ar[4], ar[5], ar[6], ar[7]);
    }
}

// ---- post layer2 + classifier (4 lanes/node) ----
__global__ __launch_bounds__(256) void post2_kernel(
    const float* __restrict__ agg, const int* __restrict__ deg,
    const float* __restrict__ hr, const float* __restrict__ b2,
    const float* __restrict__ Wc, const float* __restrict__ bc,
    float* __restrict__ h2out, float* __restrict__ outp)
{
    __shared__ float hs[PPB][DH + 1];
    int t = threadIdx.x;
    int n = t >> 2;
    int sub = t & 3;
    int g = blockIdx.x * PPB + n;
    bool valid = g < NN;

    float o[8];
#pragma unroll
    for (int j = 0; j < 8; ++j) o[j] = 0.f;
    if (valid) {
        float inv = 1.0f / fmaxf((float)deg[g], 1.0f);
        const float4* ag4 = reinterpret_cast<const float4*>(agg + (size_t)g * DH + sub * 8);
        const float4* hr4 = reinterpret_cast<const float4*>(hr  + (size_t)g * DH + sub * 8);
        const float*  bp  = b2 + sub * 8;
#pragma unroll
        for (int q = 0; q < 2; ++q) {
            float4 a = ag4[q]; float4 r = hr4[q];
            o[q*4+0] = fmaf(a.x, inv, bp[q*4+0] + r.x);
            o[q*4+1] = fmaf(a.y, inv, bp[q*4+1] + r.y);
            o[q*4+2] = fmaf(a.z, inv, bp[q*4+2] + r.z);
            o[q*4+3] = fmaf(a.w, inv, bp[q*4+3] + r.w);
        }
    }
    float ss = 0.f;
#pragma unroll
    for (int j = 0; j < 8; ++j) ss += o[j] * o[j];
    ss += __shfl_xor(ss, 1);
    ss += __shfl_xor(ss, 2);
    float rn = 1.0f / fmaxf(sqrtf(ss), 1e-12f);
    float h[8];
#pragma unroll
    for (int j = 0; j < 8; ++j) h[j] = tanhf(o[j] * rn);
#pragma unroll
    for (int j = 0; j < 8; ++j) hs[n][sub * 8 + j] = h[j];
    if (valid) {
        float4* h2o = reinterpret_cast<float4*>(h2out + (size_t)g * DH + sub * 8);
        h2o[0] = make_float4(h[0], h[1], h[2], h[3]);
        h2o[1] = make_float4(h[4], h[5], h[6], h[7]);
    }
    __syncthreads();

    float z[5];
#pragma unroll
    for (int q = 0; q < 5; ++q) z[q] = bc[sub * 5 + q];
    for (int k = 0; k < DH; ++k) {
        float hk = hs[n][k];
        const float* wc = Wc + k * DOUT + sub * 5;
#pragma unroll
        for (int q = 0; q < 5; ++q) z[q] = fmaf(hk, wc[q], z[q]);
    }
    float m = z[0];
#pragma unroll
    for (int q = 1; q < 5; ++q) m = fmaxf(m, z[q]);
    m = fmaxf(m, __shfl_xor(m, 1));
    m = fmaxf(m, __shfl_xor(m, 2));
    float s = 0.f;
#pragma unroll
    for (int q = 0; q < 5; ++q) s += expf(z[q] - m);
    s += __shfl_xor(s, 1);
    s += __shfl_xor(s, 2);
    float lse = m + logf(s);
    if (valid) {
        float* orow = outp + (size_t)g * DOUT + sub * 5;
#pragma unroll
        for (int q = 0; q < 5; ++q) orow[q] = z[q] - lse;
    }
}

extern "C" void kernel_launch(void* const* d_in, const int* in_sizes, int n_in,
                              void* d_out, int out_size, void* d_ws, size_t ws_size,
                              hipStream_t stream) {
    const float* x   = (const float*)d_in[0];
    const int*   ei  = (const int*)d_in[1];
    const float* W1l = (const float*)d_in[2];
    const float* b1  = (const float*)d_in[3];
    const float* W1r = (const float*)d_in[4];
    const float* W2l = (const float*)d_in[5];
    const float* b2  = (const float*)d_in[6];
    const float* W2r = (const float*)d_in[7];
    const float* Wc  = (const float*)d_in[8];
    const float* bc  = (const float*)d_in[9];

    float* outp = (float*)d_out;                          // [NN, 20]
    float* hout = outp + (size_t)NN * DOUT;               // [NN, 32]

    // workspace layout (round-12 proven layout)
    unsigned short* xlbf = (unsigned short*)d_ws;         // NN*DH bf16 (6.4 MB)
    float* xr      = (float*)(xlbf + (size_t)NN * DH);    // NN*DH f32 (also hr)
    float* agg     = xr + (size_t)NN * DH;                // NN*DH f32 (aliases csrtmp)
    unsigned* csrtmp = (unsigned*)agg;                    // NE u32
    int* csrsrc    = (int*)(agg + (size_t)NN * DH);       // NE
    int* deg       = csrsrc + NE;                         // NN
    int* start     = deg + NN;                            // NN
    int* counts    = start + NN;                          // NBLK*NB
    int* offs      = counts + NBLK * NB;                  // NB*NBLK
    int* totals    = offs + NB * NBLK;                    // NB
    int* bases     = totals + NB;                         // NB+1

    const int lin1Blocks   = (NN + NPB - 1) / NPB;        // 1563
    const int postBlocks   = (NN + PPB - 1) / PPB;        // 1563
    const int gatherBlocks = (NN * 8 + 255) / 256;        // 3125

    lin1_kernel<<<lin1Blocks, 256, 0, stream>>>(x, W1l, W1r, xlbf, xr);

    countA_kernel<<<NBLK, 256, 0, stream>>>(ei, counts);
    scanB1_kernel<<<NB, 256, 0, stream>>>(counts, offs, totals);
    scanB2_kernel<<<1, 64, 0, stream>>>(totals, bases);
    scatterC_kernel<<<NBLK, 256, 0, stream>>>(ei, offs, bases, csrtmp);
    regroupD_kernel<<<NBUSE, 256, 0, stream>>>(csrtmp, bases, csrsrc, deg, start);

    gather_kernel<<<gatherBlocks, 256, 0, stream>>>(start, deg, csrsrc, xlbf, agg);
    post1_kernel<<<postBlocks, 256, 0, stream>>>(agg, deg, xr, b1, W2l, W2r, xlbf, xr);

    gather_kernel<<<gatherBlocks, 256, 0, stream>>>(start, deg, csrsrc, xlbf, agg);
    post2_kernel<<<postBlocks, 256, 0, stream>>>(agg, deg, xr, b2, Wc, bc, hout, outp);
}

// Round 15
// 207.627 us; speedup vs baseline: 7.0770x; 1.0980x over previous
//
#include <hip/hip_runtime.h>
#include <cmath>

constexpr int NN   = 100000;
constexpr int NE   = 3200000;
constexpr int DIN  = 128;
constexpr int DH   = 32;
constexpr int DOUT = 20;

constexpr int NB    = 392;                 // coarse buckets: dst>>8 -> 0..390 (+1 pad)
constexpr int NBUSE = (NN + 255) / 256;    // 391 buckets actually used
constexpr int NBLK  = 256;                 // phase A/C blocks
constexpr int SLICE = NE / NBLK;           // 12500 edges per block (exact)

constexpr int NPB = 64;                    // nodes per lin1 block
constexpr int XSB = 136;                   // bf16 LDS row stride (16B-aligned, 2-way banks)
constexpr int PPB = 64;                    // nodes per post block (4 lanes/node)

typedef __attribute__((ext_vector_type(8))) short short8v;   // 8 bf16 (4 VGPRs)
typedef __attribute__((ext_vector_type(4))) float f32x4;     // MFMA accumulator

__device__ inline unsigned short f2bf(float f) {           // RNE float->bf16
    unsigned u = __builtin_bit_cast(unsigned, f);
    unsigned r = 0x7FFFu + ((u >> 16) & 1u);
    return (unsigned short)((u + r) >> 16);
}
__device__ inline float bflo(unsigned u) {                 // low ushort -> float
    return __builtin_bit_cast(float, u << 16);
}
__device__ inline float bfhi(unsigned u) {                 // high ushort -> float
    return __builtin_bit_cast(float, u & 0xFFFF0000u);
}

// ---------------- layer-1 projections via MFMA: xl(bf16)=x@W1l, xr(f32)=x@W1r ----------
__global__ __launch_bounds__(256, 4) void lin1_kernel(
    const float* __restrict__ x, const float* __restrict__ Wl,
    const float* __restrict__ Wr, unsigned short* __restrict__ xlbf,
    float* __restrict__ xr)
{
    __shared__ unsigned short xs[NPB * XSB];   // 17408 B
    int t = threadIdx.x;
    int nodeBase = blockIdx.x * NPB;

    const float4* x4 = reinterpret_cast<const float4*>(x) + (size_t)nodeBase * (DIN / 4);
    for (int i = t; i < NPB * (DIN / 4); i += 256) {
        int n = i >> 5, c = i & 31;
        float4 v = make_float4(0.f, 0.f, 0.f, 0.f);
        if (nodeBase + n < NN) v = x4[i];
        unsigned lo = (unsigned)f2bf(v.x) | ((unsigned)f2bf(v.y) << 16);
        unsigned hi = (unsigned)f2bf(v.z) | ((unsigned)f2bf(v.w) << 16);
        *reinterpret_cast<uint2*>(&xs[n * XSB + c * 4]) = make_uint2(lo, hi);
    }
    __syncthreads();

    int wv   = t >> 6;                 // 0..3
    int lane = t & 63;
    const float* W = (wv & 2) ? Wr : Wl;
    int jbase = (wv & 1) * 16;
    int ncol  = jbase + (lane & 15);   // B: col = lane&15
    int krow  = (lane >> 4) * 8;       // B/A: k-chunk = (lane>>4)*8

    short8v bfrag[4];
#pragma unroll
    for (int ks = 0; ks < 4; ++ks) {
        const float* wp = W + (ks * 32 + krow) * DH + ncol;
        short8v f;
#pragma unroll
        for (int e = 0; e < 8; ++e) f[e] = (short)f2bf(wp[e * DH]);
        bfrag[ks] = f;
    }

    f32x4 acc[4];
#pragma unroll
    for (int m = 0; m < 4; ++m) acc[m] = f32x4{0.f, 0.f, 0.f, 0.f};

#pragma unroll
    for (int m = 0; m < 4; ++m) {
        int row = m * 16 + (lane & 15);
#pragma unroll
        for (int ks = 0; ks < 4; ++ks) {
            short8v a = *reinterpret_cast<const short8v*>(&xs[row * XSB + ks * 32 + krow]);
            acc[m] = __builtin_amdgcn_mfma_f32_16x16x32_bf16(a, bfrag[ks], acc[m], 0, 0, 0);
        }
    }

#pragma unroll
    for (int m = 0; m < 4; ++m) {
        int rbase = m * 16 + (lane >> 4) * 4;
#pragma unroll
        for (int r = 0; r < 4; ++r) {
            int node = nodeBase + rbase + r;
            if (node < NN) {
                float v = acc[m][r];
                if (wv & 2) xr[(size_t)node * DH + ncol] = v;
                else        xlbf[(size_t)node * DH + ncol] = f2bf(v);
            }
        }
    }
}

// ---------------- phase A: per-block coarse-bucket histogram (1024 thr) ----------------
__global__ __launch_bounds__(1024) void countA_kernel(
    const int* __restrict__ ei, int* __restrict__ counts)
{
    __shared__ int h[NB];
    int blk = blockIdx.x, t = threadIdx.x;
    for (int i = t; i < NB; i += 1024) h[i] = 0;
    __syncthreads();
    int base = blk * SLICE;
    for (int i = base + t; i < base + SLICE; i += 1024) {
        int dst = ei[NE + i];
        atomicAdd(&h[dst >> 8], 1);
    }
    __syncthreads();
    for (int i = t; i < NB; i += 1024) counts[blk * NB + i] = h[i];
}

// ------- phase B1: per-bucket exclusive scan over 256 block counts -------
__global__ __launch_bounds__(256) void scanB1_kernel(
    const int* __restrict__ counts, int* __restrict__ offs, int* __restrict__ totals)
{
    __shared__ int sdata[256];
    int b = blockIdx.x, t = threadIdx.x;
    int v = counts[t * NB + b];
    sdata[t] = v;
    __syncthreads();
    for (int off = 1; off < 256; off <<= 1) {
        int tmp = (t >= off) ? sdata[t - off] : 0;
        __syncthreads();
        sdata[t] += tmp;
        __syncthreads();
    }
    offs[b * 256 + t] = sdata[t] - v;
    if (t == 255) totals[b] = sdata[255];
}

// ------- phase B2: exclusive scan of bucket totals (tiny) -------
__global__ void scanB2_kernel(const int* __restrict__ totals, int* __restrict__ bases)
{
    if (threadIdx.x == 0 && blockIdx.x == 0) {
        int acc = 0;
        for (int i = 0; i < NB; ++i) { bases[i] = acc; acc += totals[i]; }
        bases[NB] = acc;
    }
}

// ------- phase C: rank-based scatter into per-(block,bucket) regions (1024 thr) -------
__global__ __launch_bounds__(1024) void scatterC_kernel(
    const int* __restrict__ ei, const int* __restrict__ offs,
    const int* __restrict__ bases, unsigned* __restrict__ csrtmp)
{
    __shared__ int cnt[NB];
    __shared__ int wbase[NB];
    int blk = blockIdx.x, t = threadIdx.x;
    for (int i = t; i < NB; i += 1024) {
        cnt[i] = 0;
        wbase[i] = bases[i] + offs[i * 256 + blk];
    }
    __syncthreads();
    int base = blk * SLICE;
    for (int i = base + t; i < base + SLICE; i += 1024) {
        int dst = ei[NE + i];
        int src = ei[i];
        int b = dst >> 8;
        int r = atomicAdd(&cnt[b], 1);                       // LDS atomic
        csrtmp[wbase[b] + r] = ((unsigned)(dst & 255) << 17) | (unsigned)src;
    }
}

// ------- phase D: regroup within bucket -> final CSR + start + deg (1024 thr) -------
__global__ __launch_bounds__(1024) void regroupD_kernel(
    const unsigned* __restrict__ csrtmp, const int* __restrict__ bases,
    int* __restrict__ csrsrc, int* __restrict__ deg, int* __restrict__ start)
{
    __shared__ int h[256];
    __shared__ int sdata[256];
    int b = blockIdx.x, t = threadIdx.x;
    int lo = bases[b], hi = bases[b + 1];
    if (t < 256) h[t] = 0;
    __syncthreads();
    for (int i = lo + t; i < hi; i += 1024)
        atomicAdd(&h[csrtmp[i] >> 17], 1);
    __syncthreads();
    int v = 0;
    if (t < 256) { v = h[t]; sdata[t] = v; }
    __syncthreads();
    for (int off = 1; off < 256; off <<= 1) {
        int tmp = 0;
        if (t < 256 && t >= off) tmp = sdata[t - off];
        __syncthreads();
        if (t < 256) sdata[t] += tmp;
        __syncthreads();
    }
    if (t < 256) {
        int ex = sdata[t] - v;
        int node = b * 256 + t;
        if (node < NN) { start[node] = lo + ex; deg[node] = v; }
        h[t] = ex;
    }
    __syncthreads();
    for (int i = lo + t; i < hi; i += 1024) {
        unsigned u = csrtmp[i];
        int r = atomicAdd(&h[u >> 17], 1);   // LDS atomic
        csrsrc[lo + r] = (int)(u & 0x1FFFFu);
    }
}

// ------- gather (bf16 feat rows, 64 B/row), 8-way unrolled for MLP -------
__global__ __launch_bounds__(256) void gather_kernel(
    const int* __restrict__ start, const int* __restrict__ deg,
    const int* __restrict__ csrsrc, const unsigned short* __restrict__ feat,
    float* __restrict__ agg)
{
    int tid = blockIdx.x * 256 + threadIdx.x;
    int g = tid >> 3;            // node
    int c = tid & 7;             // uint2 chunk (4 bf16) of the 32-dim row
    if (g >= NN) return;
    int s = start[g];
    int e = s + deg[g];
    const uint2* f2 = reinterpret_cast<const uint2*>(feat);
    float4 a0 = make_float4(0.f, 0.f, 0.f, 0.f);
    float4 a1 = make_float4(0.f, 0.f, 0.f, 0.f);
    float4 a2 = make_float4(0.f, 0.f, 0.f, 0.f);
    float4 a3 = make_float4(0.f, 0.f, 0.f, 0.f);
    int i = s;
    for (; i + 8 <= e; i += 8) {
        int sx[8];
#pragma unroll
        for (int q = 0; q < 8; ++q) sx[q] = csrsrc[i + q];
        uint2 vv[8];
#pragma unroll
        for (int q = 0; q < 8; ++q) vv[q] = f2[(size_t)sx[q] * 8 + c];
        a0.x += bflo(vv[0].x) + bflo(vv[4].x); a0.y += bfhi(vv[0].x) + bfhi(vv[4].x);
        a0.z += bflo(vv[0].y) + bflo(vv[4].y); a0.w += bfhi(vv[0].y) + bfhi(vv[4].y);
        a1.x += bflo(vv[1].x) + bflo(vv[5].x); a1.y += bfhi(vv[1].x) + bfhi(vv[5].x);
        a1.z += bflo(vv[1].y) + bflo(vv[5].y); a1.w += bfhi(vv[1].y) + bfhi(vv[5].y);
        a2.x += bflo(vv[2].x) + bflo(vv[6].x); a2.y += bfhi(vv[2].x) + bfhi(vv[6].x);
        a2.z += bflo(vv[2].y) + bflo(vv[6].y); a2.w += bfhi(vv[2].y) + bfhi(vv[6].y);
        a3.x += bflo(vv[3].x) + bflo(vv[7].x); a3.y += bfhi(vv[3].x) + bfhi(vv[7].x);
        a3.z += bflo(vv[3].y) + bflo(vv[7].y); a3.w += bfhi(vv[3].y) + bfhi(vv[7].y);
    }
    for (; i < e; ++i) {
        int s0 = csrsrc[i];
        uint2 v0 = f2[(size_t)s0 * 8 + c];
        a0.x += bflo(v0.x); a0.y += bfhi(v0.x); a0.z += bflo(v0.y); a0.w += bfhi(v0.y);
    }
    a0.x += a1.x + a2.x + a3.x;
    a0.y += a1.y + a2.y + a3.y;
    a0.z += a1.z + a2.z + a3.z;
    a0.w += a1.w + a2.w + a3.w;
    reinterpret_cast<float4*>(agg)[(size_t)g * 8 + c] = a0;
}

// ---- post layer1 (4 lanes/node): o = agg/deg + b1 + xr; h1 = tanh(l2norm(o));
//      hl(bf16) = h1@W2l, hr(f32) = h1@W2r ----
__global__ __launch_bounds__(256) void post1_kernel(
    const float* __restrict__ agg, const int* __restrict__ deg,
    const float* __restrict__ xr, const float* __restrict__ b1,
    const float* __restrict__ W2l, const float* __restrict__ W2r,
    unsigned short* __restrict__ hlbf, float* __restrict__ hr)
{
    __shared__ float hs[PPB][DH + 1];
    int t = threadIdx.x;
    int n = t >> 2;                    // local node 0..63
    int sub = t & 3;                   // dim group: [sub*8, sub*8+8)
    int g = blockIdx.x * PPB + n;
    bool valid = g < NN;

    float o[8];
#pragma unroll
    for (int j = 0; j < 8; ++j) o[j] = 0.f;
    if (valid) {
        float inv = 1.0f / fmaxf((float)deg[g], 1.0f);
        const float4* ag4 = reinterpret_cast<const float4*>(agg + (size_t)g * DH + sub * 8);
        const float4* xr4 = reinterpret_cast<const float4*>(xr  + (size_t)g * DH + sub * 8);
        const float*  bp  = b1 + sub * 8;
#pragma unroll
        for (int q = 0; q < 2; ++q) {
            float4 a = ag4[q]; float4 r = xr4[q];
            o[q*4+0] = fmaf(a.x, inv, bp[q*4+0] + r.x);
            o[q*4+1] = fmaf(a.y, inv, bp[q*4+1] + r.y);
            o[q*4+2] = fmaf(a.z, inv, bp[q*4+2] + r.z);
            o[q*4+3] = fmaf(a.w, inv, bp[q*4+3] + r.w);
        }
    }
    float ss = 0.f;
#pragma unroll
    for (int j = 0; j < 8; ++j) ss += o[j] * o[j];
    ss += __shfl_xor(ss, 1);
    ss += __shfl_xor(ss, 2);
    float rn = 1.0f / fmaxf(sqrtf(ss), 1e-12f);
    float h[8];
#pragma unroll
    for (int j = 0; j < 8; ++j) h[j] = tanhf(o[j] * rn);
#pragma unroll
    for (int j = 0; j < 8; ++j) hs[n][sub * 8 + j] = h[j];
    __syncthreads();

    float al[8], ar[8];
#pragma unroll
    for (int j = 0; j < 8; ++j) { al[j] = 0.f; ar[j] = 0.f; }
    for (int k = 0; k < DH; ++k) {
        float hk = hs[n][k];
        const float4* wl4 = reinterpret_cast<const float4*>(W2l + k * DH + sub * 8);
        const float4* wr4 = reinterpret_cast<const float4*>(W2r + k * DH + sub * 8);
#pragma unroll
        for (int q = 0; q < 2; ++q) {
            float4 wl = wl4[q], wr = wr4[q];
            al[q*4+0] = fmaf(hk, wl.x, al[q*4+0]);
            al[q*4+1] = fmaf(hk, wl.y, al[q*4+1]);
            al[q*4+2] = fmaf(hk, wl.z, al[q*4+2]);
            al[q*4+3] = fmaf(hk, wl.w, al[q*4+3]);
            ar[q*4+0] = fmaf(hk, wr.x, ar[q*4+0]);
            ar[q*4+1] = fmaf(hk, wr.y, ar[q*4+1]);
            ar[q*4+2] = fmaf(hk, wr.z, ar[q*4+2]);
            ar[q*4+3] = fmaf(hk, wr.w, ar[q*4+3]);
        }
    }
    if (valid) {
        unsigned pk[4];
#pragma unroll
        for (int q = 0; q < 4; ++q)
            pk[q] = (unsigned)f2bf(al[q*2]) | ((unsigned)f2bf(al[q*2+1]) << 16);
        *reinterpret_cast<uint4*>(hlbf + (size_t)g * DH + sub * 8) =
            make_uint4(pk[0], pk[1], pk[2], pk[3]);
        float4* hr4 = reinterpret_cast<float4*>(hr + (size_t)g * DH + sub * 8);
        hr4[0] = make_float4(ar[0], ar[1], ar[2], ar[3]);
        hr4[1] = make_float4(ar[4], ar[5], ar[6], ar[7]);
    }
}

// ---- post layer2 + classifier (4 lanes/node) ----
__global__ __launch_bounds__(256) void post2_kernel(
    const float* __restrict__ agg, const int* __restrict__ deg,
    const float* __restrict__ hr, const float* __restrict__ b2,
    const float* __restrict__ Wc, const float* __restrict__ bc,
    float* __restrict__ h2out, float* __restrict__ outp)
{
    __shared__ float hs[PPB][DH + 1];
    int t = threadIdx.x;
    int n = t >> 2;
    int sub = t & 3;
    int g = blockIdx.x * PPB + n;
    bool valid = g < NN;

    float o[8];
#pragma unroll
    for (int j = 0; j < 8; ++j) o[j] = 0.f;
    if (valid) {
        float inv = 1.0f / fmaxf((float)deg[g], 1.0f);
        const float4* ag4 = reinterpret_cast<const float4*>(agg + (size_t)g * DH + sub * 8);
        const float4* hr4 = reinterpret_cast<const float4*>(hr  + (size_t)g * DH + sub * 8);
        const float*  bp  = b2 + sub * 8;
#pragma unroll
        for (int q = 0; q < 2; ++q) {
            float4 a = ag4[q]; float4 r = hr4[q];
            o[q*4+0] = fmaf(a.x, inv, bp[q*4+0] + r.x);
            o[q*4+1] = fmaf(a.y, inv, bp[q*4+1] + r.y);
            o[q*4+2] = fmaf(a.z, inv, bp[q*4+2] + r.z);
            o[q*4+3] = fmaf(a.w, inv, bp[q*4+3] + r.w);
        }
    }
    float ss = 0.f;
#pragma unroll
    for (int j = 0; j < 8; ++j) ss += o[j] * o[j];
    ss += __shfl_xor(ss, 1);
    ss += __shfl_xor(ss, 2);
    float rn = 1.0f / fmaxf(sqrtf(ss), 1e-12f);
    float h[8];
#pragma unroll
    for (int j = 0; j < 8; ++j) h[j] = tanhf(o[j] * rn);
#pragma unroll
    for (int j = 0; j < 8; ++j) hs[n][sub * 8 + j] = h[j];
    if (valid) {
        float4* h2o = reinterpret_cast<float4*>(h2out + (size_t)g * DH + sub * 8);
        h2o[0] = make_float4(h[0], h[1], h[2], h[3]);
        h2o[1] = make_float4(h[4], h[5], h[6], h[7]);
    }
    __syncthreads();

    float z[5];
#pragma unroll
    for (int q = 0; q < 5; ++q) z[q] = bc[sub * 5 + q];
    for (int k = 0; k < DH; ++k) {
        float hk = hs[n][k];
        const float* wc = Wc + k * DOUT + sub * 5;
#pragma unroll
        for (int q = 0; q < 5; ++q) z[q] = fmaf(hk, wc[q], z[q]);
    }
    float m = z[0];
#pragma unroll
    for (int q = 1; q < 5; ++q) m = fmaxf(m, z[q]);
    m = fmaxf(m, __shfl_xor(m, 1));
    m = fmaxf(m, __shfl_xor(m, 2));
    float s = 0.f;
#pragma unroll
    for (int q = 0; q < 5; ++q) s += expf(z[q] - m);
    s += __shfl_xor(s, 1);
    s += __shfl_xor(s, 2);
    float lse = m + logf(s);
    if (valid) {
        float* orow = outp + (size_t)g * DOUT + sub * 5;
#pragma unroll
        for (int q = 0; q < 5; ++q) orow[q] = z[q] - lse;
    }
}

extern "C" void kernel_launch(void* const* d_in, const int* in_sizes, int n_in,
                              void* d_out, int out_size, void* d_ws, size_t ws_size,
                              hipStream_t stream) {
    const float* x   = (const float*)d_in[0];
    const int*   ei  = (const int*)d_in[1];
    const float* W1l = (const float*)d_in[2];
    const float* b1  = (const float*)d_in[3];
    const float* W1r = (const float*)d_in[4];
    const float* W2l = (const float*)d_in[5];
    const float* b2  = (const float*)d_in[6];
    const float* W2r = (const float*)d_in[7];
    const float* Wc  = (const float*)d_in[8];
    const float* bc  = (const float*)d_in[9];

    float* outp = (float*)d_out;                          // [NN, 20]
    float* hout = outp + (size_t)NN * DOUT;               // [NN, 32]

    // workspace layout (round-12 proven layout)
    unsigned short* xlbf = (unsigned short*)d_ws;         // NN*DH bf16 (6.4 MB)
    float* xr      = (float*)(xlbf + (size_t)NN * DH);    // NN*DH f32 (also hr)
    float* agg     = xr + (size_t)NN * DH;                // NN*DH f32 (aliases csrtmp)
    unsigned* csrtmp = (unsigned*)agg;                    // NE u32
    int* csrsrc    = (int*)(agg + (size_t)NN * DH);       // NE
    int* deg       = csrsrc + NE;                         // NN
    int* start     = deg + NN;                            // NN
    int* counts    = start + NN;                          // NBLK*NB
    int* offs      = counts + NBLK * NB;                  // NB*NBLK
    int* totals    = offs + NB * NBLK;                    // NB
    int* bases     = totals + NB;                         // NB+1

    const int lin1Blocks   = (NN + NPB - 1) / NPB;        // 1563
    const int postBlocks   = (NN + PPB - 1) / PPB;        // 1563
    const int gatherBlocks = (NN * 8 + 255) / 256;        // 3125

    lin1_kernel<<<lin1Blocks, 256, 0, stream>>>(x, W1l, W1r, xlbf, xr);

    countA_kernel<<<NBLK, 1024, 0, stream>>>(ei, counts);
    scanB1_kernel<<<NB, 256, 0, stream>>>(counts, offs, totals);
    scanB2_kernel<<<1, 64, 0, stream>>>(totals, bases);
    scatterC_kernel<<<NBLK, 1024, 0, stream>>>(ei, offs, bases, csrtmp);
    regroupD_kernel<<<NBUSE, 1024, 0, stream>>>(csrtmp, bases, csrsrc, deg, start);

    gather_kernel<<<gatherBlocks, 256, 0, stream>>>(start, deg, csrsrc, xlbf, agg);
    post1_kernel<<<postBlocks, 256, 0, stream>>>(agg, deg, xr, b1, W2l, W2r, xlbf, xr);

    gather_kernel<<<gatherBlocks, 256, 0, stream>>>(start, deg, csrsrc, xlbf, agg);
    post2_kernel<<<postBlocks, 256, 0, stream>>>(agg, deg, xr, b2, Wc, bc, hout, outp);
}